// Round 4
// baseline (53.945 us; speedup 1.0000x reference)
//
#include <hip/hip_runtime.h>

// Problem constants (static per reference)
constexpr int B_DIM   = 32;
constexpr int M_EDGES = 4096;     // edges per batch (2^12)
constexpr int F_DIM   = 64;
constexpr int N_ATOMS = 128;

constexpr int TOTAL_EDGES = B_DIM * M_EDGES;               // 131072
constexpr int CELLS       = B_DIM * N_ATOMS * N_ATOMS;     // 524288
constexpr unsigned int POOL_CAP = 8192;                    // overflow pool entries

using f32x4 = __attribute__((ext_vector_type(4))) float;

// Packed record per cell: uint2
//   w0 = count (low 16) | edge-slot0 local id m (high 16)
//   w1 = slot1 m (low 16) | slot2 m (high 16)
// Local id m = e & 4095 (12 bits); global e = (cell>>14)*4096 + m.
// Counter carries can't reach bit 16 (per-cell count << 65536).
// Cells with count > 3 spill edges 4.. into an atomic-append pool of
// (cell, global edge) pairs; only those cells scan the pool (~90 entries).

// ---------------------------------------------------------------------------
// Kernel 1: bin edges into packed records.
// ---------------------------------------------------------------------------
__global__ __launch_bounds__(256) void bin_edges_kernel(
    const int*          __restrict__ pair,      // [B, M, 2] int32
    unsigned int*       __restrict__ packed,    // [CELLS * 2]
    unsigned int*       __restrict__ pool_cnt,  // [1]
    unsigned long long* __restrict__ pool)      // [POOL_CAP]
{
    const int e = blockIdx.x * 256 + threadIdx.x;   // grid == TOTAL_EDGES
    const int2 ij = ((const int2*)pair)[e];
    const int b = e >> 12;
    const unsigned int m = (unsigned int)(e & (M_EDGES - 1));

    const int cell = (b << 14) | (ij.x << 7) | ij.y;
    unsigned int* rec = packed + 2 * (size_t)cell;

    const unsigned int old = atomicAdd(&rec[0], 1u);
    const unsigned int pos = old & 0xFFFFu;

    if (pos == 0u) {
        atomicOr(&rec[0], m << 16);
    } else if (pos == 1u) {
        atomicOr(&rec[1], m);
    } else if (pos == 2u) {
        atomicOr(&rec[1], m << 16);
    } else {
        const unsigned int pi = atomicAdd(pool_cnt, 1u);
        if (pi < POOL_CAP)
            pool[pi] = ((unsigned long long)(unsigned int)cell << 32) | (unsigned int)e;
    }
}

// ---------------------------------------------------------------------------
// Kernel 2: 16 threads per cell, one float4 of F each. One dense uint2 read
// gives count + up to 3 edge ids; unused ids clamp to id0 (aliases the
// already-fetched line) and blend via 0/1 scale -> no branches, full ILP.
// Output written exactly once (the write IS the zero-fill).
// ---------------------------------------------------------------------------
__global__ __launch_bounds__(256) void gather_write_kernel(
    const float*              __restrict__ edge,      // [B, M, F]
    const unsigned int*       __restrict__ packed,    // [CELLS * 2]
    const unsigned int*       __restrict__ pool_cnt,  // [1]
    const unsigned long long* __restrict__ pool,      // [POOL_CAP]
    float*                    __restrict__ out)       // [B, N, N, F]
{
    const int tid  = blockIdx.x * 256 + threadIdx.x;
    const int cell = tid >> 4;          // 16 threads per cell
    const int q    = tid & 15;          // which float4 of the 64 features

    const uint2 r = ((const uint2*)packed)[cell];   // dense, coalesced
    const int cnt = (int)(r.x & 0xFFFFu);

    f32x4 acc = (f32x4)0.0f;
    const f32x4* ef = (const f32x4*)edge;

    if (cnt > 0) {
        const int ebase = (cell >> 14) << 12;       // batch * M_EDGES
        const int e0 = ebase + (int)(r.x >> 16);
        const int e1 = cnt > 1 ? ebase + (int)(r.y & 0xFFFFu) : e0;
        const int e2 = cnt > 2 ? ebase + (int)(r.y >> 16)     : e0;

        const f32x4 a0 = ef[(size_t)e0 * 16 + q];   // independent loads
        const f32x4 a1 = ef[(size_t)e1 * 16 + q];
        const f32x4 a2 = ef[(size_t)e2 * 16 + q];

        acc = a0;
        acc += a1 * (cnt > 1 ? 1.0f : 0.0f);
        acc += a2 * (cnt > 2 ? 1.0f : 0.0f);

        if (cnt > 3) {                              // ~84 cells in the whole problem
            unsigned int pc = *pool_cnt;
            pc = pc > POOL_CAP ? POOL_CAP : pc;
            for (unsigned int t = 0; t < pc; ++t) {
                const unsigned long long ent = pool[t];
                if ((int)(ent >> 32) == cell)
                    acc += ef[(size_t)(unsigned int)ent * 16 + q];
            }
        }
    }

    ((f32x4*)out)[(size_t)cell * 16 + q] = acc;
}

extern "C" void kernel_launch(void* const* d_in, const int* in_sizes, int n_in,
                              void* d_out, int out_size, void* d_ws, size_t ws_size,
                              hipStream_t stream) {
    const float* edge = (const float*)d_in[0];
    const int*   pair = (const int*)d_in[1];
    float*       out  = (float*)d_out;

    // Workspace layout:
    //   [0, 4 MiB)              packed records (uint2 x CELLS)
    //   [4 MiB, 4 MiB + 8)      pool counter
    //   [4 MiB + 8, + 64 KiB)   overflow pool (u64 x POOL_CAP)
    unsigned int*       packed   = (unsigned int*)d_ws;
    unsigned int*       pool_cnt = (unsigned int*)((char*)d_ws + (size_t)CELLS * 8);
    unsigned long long* pool     = (unsigned long long*)((char*)d_ws + (size_t)CELLS * 8 + 8);

    // Zero packed records + pool counter each call (pool entries gated by cnt).
    hipMemsetAsync(d_ws, 0, (size_t)CELLS * 8 + 16, stream);

    bin_edges_kernel<<<TOTAL_EDGES / 256, 256, 0, stream>>>(pair, packed, pool_cnt, pool);

    gather_write_kernel<<<(CELLS * 16) / 256, 256, 0, stream>>>(edge, packed, pool_cnt, pool, out);
}